// Round 15
// baseline (400.294 us; speedup 1.0000x reference)
//
#include <hip/hip_runtime.h>
#include <hip/hip_bf16.h>

typedef __hip_bfloat16 bf16;
typedef __attribute__((ext_vector_type(8))) short short8v;
typedef __attribute__((ext_vector_type(4))) float f32x4;
typedef unsigned int uint;
typedef unsigned long long u64;

#define BATCH 8
#define NPTS 2048
#define KNN 20
#define NK (NPTS*KNN)      // 40960
#define P4 (BATCH*NK)      // 327680
#define BN_TOT (BATCH*NPTS) // 16384

union BU { bf16 h; unsigned short u; };
__device__ __forceinline__ unsigned short f2bf(float f){
    BU bu; bu.h = __float2bfloat16(f); return bu.u;
}
__device__ __forceinline__ float bfu2f(unsigned short u){
    return __uint_as_float(((uint)u) << 16);
}
// monotone flip encoding: unsigned compare == float compare
__device__ __forceinline__ uint fenc(float f){
    uint b = __float_as_uint(f);
    return (b & 0x80000000u) ? ~b : (b | 0x80000000u);
}

// ---------------- init: zero shadow stats ----------------
__global__ void initK(float* __restrict__ shadow)
{
    int t = blockIdx.x*256 + threadIdx.x;
    if (t < 5*16*1024) shadow[t] = 0.f;
}

// convert W to bf16 with per-row XOR swizzle on the k index (T2-style):
// dst[co][ci ^ ((co&7)<<3)] = bf16(src[co][ci]).  Read back with same XOR.
__global__ void cvtWS(const float* __restrict__ src, short* __restrict__ dst, int Cin)
{
    int t = blockIdx.x*256 + threadIdx.x;
    int co = t / Cin, ci = t - co*Cin;
    dst[(size_t)co*Cin + (ci ^ ((co & 7) << 3))] = (short)f2bf(src[t]);
}

// ---------------- KNN v6: 2 waves per point (split-scan) + merge-path combine ----------------
// Each wave scans a disjoint 1024-candidate half, produces its EXACT top-20
// (L=4 dual-chain fast path, verified 20-chain fallback) as unique u64 keys
// (fenc(v)<<32 | ~idx) into LDS; 40 lanes then merge-rank the two sorted lists.
__global__ __launch_bounds__(512)
void knn_kernel(const float* __restrict__ x, int* __restrict__ idx)
{
    #pragma clang fp contract(off)
    __shared__ float4 sp[NPTS];               // (x,y,z,xx)  32 KB
    __shared__ u64 skeys[4][2][KNN];          // 1.28 KB
    const int b  = blockIdx.x / (NPTS/4);     // 512 blocks per batch
    const int nb = blockIdx.x % (NPTS/4);
    const float* xb = x + (size_t)b*3*NPTS;
    for (int i = threadIdx.x; i < NPTS; i += 512) {
        float y0 = xb[i], y1 = xb[NPTS+i], y2 = xb[2*NPTS+i];
        float4 p; p.x = y0; p.y = y1; p.z = y2;
        p.w = y0*y0 + y1*y1 + y2*y2;          // same op order as original xxm
        sp[i] = p;
    }
    __syncthreads();

    const int wv   = threadIdx.x >> 6;
    const int lane = threadIdx.x & 63;
    const int pidx = wv >> 1;                 // point within block (0..3)
    const int hh   = wv & 1;                  // half (0/1)
    const int n    = nb*4 + pidx;
    const int base = hh*1024;

    const float4 pn = sp[n];
    const float x0 = pn.x, x1 = pn.y, x2 = pn.z;
    const float xxn = pn.w;

    constexpr int L = 4;
    float bA[L], bB[L]; int iA[L], iB[L];
    #pragma unroll
    for (int i = 0; i < L; ++i) {
        bA[i] = -3e38f; bB[i] = -3e38f; iA[i] = 0x7fffffff; iB[i] = 0x7fffffff;
    }

    // scan this wave's half: 8 pair-iterations (16 candidates/lane)
    float4 c0 = sp[base + lane], c1 = sp[base + lane + 64];
    #pragma unroll
    for (int t = 0; t < 8; ++t) {
        float4 n0, n1;
        if (t + 1 < 8) {
            n0 = sp[base + lane + (2*t+2)*64];
            n1 = sp[base + lane + (2*t+3)*64];
        }
        int m0 = base + lane + (2*t)*64, m1 = m0 + 64;
        float dot0 = x0*c0.x + x1*c0.y + x2*c0.z;
        float v0 = -xxn - (-2.f*dot0) - c0.w;
        float dot1 = x0*c1.x + x1*c1.y + x2*c1.z;
        float v1 = -xxn - (-2.f*dot1) - c1.w;
        int mi0 = m0, mi1 = m1;
        #pragma unroll
        for (int i = 0; i < L; ++i) {         // two independent chains -> ILP
            { bool sw = v0 > bA[i];
              float tv = sw ? bA[i] : v0; int ti = sw ? iA[i] : mi0;
              bA[i] = sw ? v0 : bA[i]; iA[i] = sw ? mi0 : iA[i]; v0 = tv; mi0 = ti; }
            { bool sw = v1 > bB[i];
              float tv = sw ? bB[i] : v1; int ti = sw ? iB[i] : mi1;
              bB[i] = sw ? v1 : bB[i]; iB[i] = sw ? mi1 : iB[i]; v1 = tv; mi1 = ti; }
        }
        c0 = n0; c1 = n1;
    }

    // pack to u64 keys
    u64 kA[L], kB[L];
    #pragma unroll
    for (int i = 0; i < L; ++i) {
        kA[i] = ((u64)fenc(bA[i]) << 32) | (uint)(~iA[i]);
        kB[i] = ((u64)fenc(bB[i]) << 32) | (uint)(~iB[i]);
    }

    int popA = 0, popB = 0;
    #pragma unroll 1
    for (int s = 0; s < KNN; ++s) {
        bool useA = kA[0] >= kB[0];
        u64 my = useA ? kA[0] : kB[0];
        u64 g = my;
        #pragma unroll
        for (int off = 1; off < 64; off <<= 1) {
            u64 o = __shfl_xor(g, off);
            g = (o > g) ? o : g;
        }
        if (lane == 0) skeys[pidx][hh][s] = g;
        bool win = (my == g);
        bool pA = win && useA, pB = win && !useA;
        #pragma unroll
        for (int i = 0; i < L-1; ++i) {
            kA[i] = pA ? kA[i+1] : kA[i];
            kB[i] = pB ? kB[i+1] : kB[i];
        }
        kA[L-1] = pA ? 0ULL : kA[L-1];
        kB[L-1] = pB ? 0ULL : kB[L-1];
        popA += pA; popB += pB;
    }

    if (__any((popA >= L) || (popB >= L))) {
        // exact fallback over this wave's half: verified 20-chain + 20-round merge
        float B[KNN]; int BI[KNN];
        #pragma unroll
        for (int i = 0; i < KNN; ++i) { B[i] = -3e38f; BI[i] = 0x7fffffff; }
        #pragma unroll 1
        for (int j = 0; j < 16; ++j) {
            int m = base + lane + j*64;
            float4 p = sp[m];
            float dot = x0*p.x + x1*p.y + x2*p.z;
            float v = -xxn - (-2.f*dot) - p.w;
            int mi = m;
            #pragma unroll
            for (int i = 0; i < KNN; ++i) {
                bool sw = v > B[i];
                float tv = sw ? B[i]  : v;
                int   ti = sw ? BI[i] : mi;
                B[i]  = sw ? v  : B[i];
                BI[i] = sw ? mi : BI[i];
                v = tv; mi = ti;
            }
        }
        #pragma unroll 1
        for (int s = 0; s < KNN; ++s) {
            float mv = B[0]; int mi = BI[0];
            #pragma unroll
            for (int off = 1; off < 64; off <<= 1) {
                float ov = __shfl_xor(mv, off);
                int   oi = __shfl_xor(mi, off);
                if (ov > mv || (ov == mv && oi < mi)) { mv = ov; mi = oi; }
            }
            bool win = (B[0] == mv) && (BI[0] == mi);
            #pragma unroll
            for (int i = 0; i < KNN-1; ++i) {
                B[i]  = win ? B[i+1]  : B[i];
                BI[i] = win ? BI[i+1] : BI[i];
            }
            B[KNN-1]  = win ? -3e38f     : B[KNN-1];
            BI[KNN-1] = win ? 0x7fffffff : BI[KNN-1];
            if (lane == 0) skeys[pidx][hh][s] = ((u64)fenc(mv) << 32) | (uint)(~mi);
        }
    }
    __syncthreads();

    // merge-path: 40 lanes of each h==0 wave rank their element vs the other list.
    // Keys unique (distinct candidate indices) -> rank mapping is a bijection.
    if (hh == 0 && lane < 2*KNN) {
        bool isA = lane < KNN;
        int i = isA ? lane : lane - KNN;
        u64 key = skeys[pidx][isA ? 0 : 1][i];
        const u64* other = skeys[pidx][isA ? 1 : 0];
        int cnt = 0;
        #pragma unroll
        for (int j = 0; j < KNN; ++j) cnt += (other[j] > key) ? 1 : 0;
        int rank = i + cnt;
        if (rank < KNN)
            idx[((size_t)b*NPTS + n)*KNN + rank] = (int)(~(uint)key);
    }
}

// ---------------- conv1: edge features + 6->64 conv + FUSED layer-1 stats ----------------
__global__ __launch_bounds__(256)
void conv1T(const float* __restrict__ x, const int* __restrict__ idx,
            const float* __restrict__ W1, bf16* __restrict__ h1,
            float* __restrict__ shadow)
{
    __shared__ unsigned short lv[256][64];   // 32 KB row mirror for stats
    __shared__ float ps[4][64], pq[4][64];
    const int tid = threadIdx.x;
    int p = blockIdx.x*256 + tid;
    int b = p / NK;
    int r = p - b*NK;
    int n = r / KNN;
    int j = idx[p];
    const float* xb = x + (size_t)b*3*NPTS;
    float c0 = xb[n], c1 = xb[NPTS+n], c2 = xb[2*NPTS+n];
    float d0 = xb[j]-c0, d1 = xb[NPTS+j]-c1, d2 = xb[2*NPTS+j]-c2;
    uint4* outp = reinterpret_cast<uint4*>(reinterpret_cast<unsigned short*>(h1) + (size_t)p*64);
    uint4* lrow = reinterpret_cast<uint4*>(lv[tid]);
    #pragma unroll
    for (int ch = 0; ch < 8; ++ch) {
        uint u[4];
        #pragma unroll
        for (int q = 0; q < 4; ++q) {
            const float* wa = W1 + (ch*8 + q*2)*6;
            float a0 = wa[0]*d0 + wa[1]*d1 + wa[2]*d2 + wa[3]*c0 + wa[4]*c1 + wa[5]*c2;
            const float* wb = wa + 6;
            float a1 = wb[0]*d0 + wb[1]*d1 + wb[2]*d2 + wb[3]*c0 + wb[4]*c1 + wb[5]*c2;
            u[q] = (uint)f2bf(a0) | ((uint)f2bf(a1) << 16);
        }
        uint4 val = make_uint4(u[0], u[1], u[2], u[3]);
        outp[ch] = val;
        lrow[ch] = val;
    }
    __syncthreads();
    // transpose-reduce: thread (grp,c) sums 64 rows of channel c (2-way bank, free)
    int c = tid & 63, grp = tid >> 6;
    float s = 0.f, q = 0.f;
    #pragma unroll 8
    for (int i = 0; i < 64; ++i) {
        float v = bfu2f(lv[grp*64 + i][c]);
        s += v; q += v*v;
    }
    ps[grp][c] = s; pq[grp][c] = q;
    __syncthreads();
    if (tid < 64) {
        float S = ps[0][tid]+ps[1][tid]+ps[2][tid]+ps[3][tid];
        float Q = pq[0][tid]+pq[1][tid]+pq[2][tid]+pq[3][tid];
        float* sh = shadow + (size_t)(blockIdx.x & 15)*1024;
        atomicAdd(&sh[tid], S);
        atomicAdd(&sh[512 + tid], Q);
    }
}

// ---------------- fold shadows -> mean/rstd -> (sc,bi) f32 ----------------
__global__ void fin_kernel(const float* __restrict__ shadow,
                           const float* __restrict__ gamma, const float* __restrict__ beta,
                           float* __restrict__ scbiF, int C, float invCnt)
{
    for (int c = threadIdx.x; c < C; c += 256) {
        float s = 0.f, q = 0.f;
        #pragma unroll
        for (int i = 0; i < 16; ++i) { s += shadow[i*1024 + c]; q += shadow[i*1024 + 512 + c]; }
        float m = s*invCnt;
        float var = q*invCnt - m*m;
        float rs = rsqrtf(var + 1e-5f);
        float sc = rs * gamma[c];
        float bi = fmaf(-m, sc, beta[c]);
        scbiF[2*c] = sc; scbiF[2*c+1] = bi;
    }
}

// ---------------- MFMA GEMM v4 (r12-verified): W in LDS (swizzled), pipelined A ----------------
template<int Cout, int Cin, int M, int POOL, int NSPLIT, int KTILE, int BT, int PF>
__global__ __launch_bounds__(BT)
void gemmT(const short* __restrict__ Wb, const bf16* __restrict__ in,
           bf16* __restrict__ outT, float* __restrict__ shadow,
           float* __restrict__ pmax, float* __restrict__ pmin)
{
    constexpr int CSPL = Cout/NSPLIT;
    constexpr int NT   = CSPL/16;
    constexpr int ROWS = (BT/64)*16*M;
    constexpr int KSTOT = Cin/32;
    constexpr int KPT   = KTILE/32;          // k-steps per W tile
    constexpr int NTILE = Cin/KTILE;
    constexpr int NG    = POOL ? ROWS/KNN : 1;
    constexpr size_t WB = (size_t)CSPL*KTILE*2;
    constexpr size_t PB = POOL ? (size_t)2*ROWS*17*4 : 0;
    constexpr size_t SB = WB > PB ? WB : PB;

    __shared__ __align__(16) char smem[SB];
    short* WsmS = reinterpret_cast<short*>(smem);
    float* poolF = reinterpret_cast<float*>(smem);

    const int tid  = threadIdx.x;
    const int lane = tid & 63;
    const int g = lane >> 4, mr = lane & 15;
    const int wid = tid >> 6;
    const int rowBlk = blockIdx.x*ROWS;
    const int rowW   = rowBlk + wid*(16*M);
    const int ntBase = blockIdx.y*CSPL;
    const short* inS = reinterpret_cast<const short*>(in);

    f32x4 acc[M][NT];
    #pragma unroll
    for (int m = 0; m < M; ++m)
    #pragma unroll
    for (int i = 0; i < NT; ++i) acc[m][i] = (f32x4){0.f,0.f,0.f,0.f};

    short8v a[M], anext[M];
    if (PF) {
        #pragma unroll
        for (int m = 0; m < M; ++m)
            a[m] = *reinterpret_cast<const short8v*>(inS + (size_t)(rowW + m*16 + mr)*Cin + 8*g);
    }

    #pragma unroll 1
    for (int kt = 0; kt < NTILE; ++kt) {
        if (kt) __syncthreads();
        {
            const int ktBase = kt*KTILE;
            for (int f8 = tid; f8 < CSPL*KTILE/8; f8 += BT) {
                int f = f8*8;
                int row = f / KTILE, col = f - row*KTILE;
                short8v v = *reinterpret_cast<const short8v*>(
                    Wb + (size_t)(ntBase + row)*Cin + ktBase + col);
                *reinterpret_cast<short8v*>(WsmS + f) = v;
            }
        }
        __syncthreads();

        #pragma unroll
        for (int ksl = 0; ksl < KPT; ++ksl) {
            const int ksg = kt*KPT + ksl;
            const int k0 = ksg*32 + 8*g;
            if (!PF) {
                #pragma unroll
                for (int m = 0; m < M; ++m)
                    a[m] = *reinterpret_cast<const short8v*>(inS + (size_t)(rowW + m*16 + mr)*Cin + k0);
            } else if (ksg + 1 < KSTOT) {
                #pragma unroll
                for (int m = 0; m < M; ++m)
                    anext[m] = *reinterpret_cast<const short8v*>(inS + (size_t)(rowW + m*16 + mr)*Cin + k0 + 32);
            }
            const int kx = ksl*32 + 8*g;           // within tile
            #pragma unroll
            for (int nt = 0; nt < NT; ++nt) {
                const int brow = nt*16 + mr;
                short8v bfr = *reinterpret_cast<const short8v*>(
                    WsmS + brow*KTILE + (kx ^ ((mr & 7) << 3)));
                #pragma unroll
                for (int m = 0; m < M; ++m)
                    acc[m][nt] = __builtin_amdgcn_mfma_f32_16x16x32_bf16(a[m], bfr, acc[m][nt], 0, 0, 0);
            }
            if (PF) {
                #pragma unroll
                for (int m = 0; m < M; ++m) a[m] = anext[m];
            }
        }
    }

    // fused per-channel stats
    float* sh = shadow + (size_t)((blockIdx.x ^ blockIdx.y) & 15)*1024;
    #pragma unroll
    for (int nt = 0; nt < NT; ++nt) {
        float s = 0.f, q = 0.f;
        #pragma unroll
        for (int m = 0; m < M; ++m)
        #pragma unroll
        for (int j = 0; j < 4; ++j) { float v = acc[m][nt][j]; s += v; q += v*v; }
        s += __shfl_xor(s, 16); s += __shfl_xor(s, 32);
        q += __shfl_xor(q, 16); q += __shfl_xor(q, 32);
        if (g == 0) {
            atomicAdd(&sh[ntBase + nt*16 + mr], s);
            atomicAdd(&sh[512 + ntBase + nt*16 + mr], q);
        }
    }

    if (!POOL) {
        #pragma unroll
        for (int m = 0; m < M; ++m)
        #pragma unroll
        for (int nt = 0; nt < NT; ++nt)
        #pragma unroll
        for (int j = 0; j < 4; ++j) {
            size_t row = (size_t)rowW + m*16 + g*4 + j;
            outT[row*Cout + ntBase + nt*16 + mr] = __float2bfloat16(acc[m][nt][j]);
        }
    } else {
        // aligned pooling, 2 nt per pass; all acc indices static (rule #20 safe)
        __syncthreads();
        #pragma unroll
        for (int np = 0; np < NT/2; ++np) {
            #pragma unroll
            for (int hh = 0; hh < 2; ++hh) {
                #pragma unroll
                for (int m = 0; m < M; ++m)
                #pragma unroll
                for (int j = 0; j < 4; ++j) {
                    int row = wid*(16*M) + m*16 + g*4 + j;
                    poolF[hh*(ROWS*17) + row*17 + mr] = acc[m][np*2+hh][j];
                }
            }
            __syncthreads();
            if (tid < 2*NG*16) {
                int hh = tid / (NG*16);
                int gg = (tid >> 4) % NG;
                int cc = tid & 15;
                float mx = -3e38f, mn = 3e38f;
                #pragma unroll
                for (int kk = 0; kk < KNN; ++kk) {
                    float v = poolF[hh*(ROWS*17) + (gg*KNN + kk)*17 + cc];
                    mx = fmaxf(mx, v); mn = fminf(mn, v);
                }
                int grp = rowBlk/KNN + gg;             // flat (b,n)
                int c = ntBase + (np*2 + hh)*16 + cc;
                pmax[(size_t)grp*256 + c] = mx;
                pmin[(size_t)grp*256 + c] = mn;
            }
            __syncthreads();
        }
    }
}

// ---------------- k-maxpool into cat_T + in-place activation write-back ----------------
template<int C>
__global__ void maxpoolT(bf16* __restrict__ h, const float* __restrict__ scbiF,
                         bf16* __restrict__ catT, int coff)
{
    constexpr int PB = 256/C;
    int t = threadIdx.x;
    int c = t & (C-1);
    int bn = blockIdx.x*PB + t/C;
    float sc = scbiF[2*c], bi = scbiF[2*c+1];
    unsigned short* src = reinterpret_cast<unsigned short*>(h) + (size_t)bn*KNN*C + c;
    float best = 0.f;                        // relu floor
    #pragma unroll
    for (int kk = 0; kk < KNN; ++kk) {
        float a = fmaxf(fmaf(bfu2f(src[kk*C]), sc, bi), 0.f);
        src[kk*C] = f2bf(a);                 // write activated value back in place
        best = fmaxf(best, a);
    }
    catT[(size_t)bn*512 + coff + c] = __float2bfloat16(best);
}

// ---------------- layer-4 pooled raw -> BN+ReLU -> cat_T[256:512] ----------------
__global__ void cat4T(const float* __restrict__ pmax, const float* __restrict__ pmin,
                      const float* __restrict__ scbiF, const float* __restrict__ g4,
                      bf16* __restrict__ catT)
{
    int t = blockIdx.x*256 + threadIdx.x;   // bn*256 + c
    int c = t & 255, bn = t >> 8;
    float sc = scbiF[2*c], bi = scbiF[2*c+1];
    float v = (g4[c] >= 0.f) ? pmax[t] : pmin[t];
    catT[(size_t)bn*512 + 256 + c] = __float2bfloat16(fmaxf(fmaf(v, sc, bi), 0.f));
}

// ---------------- final BN+ReLU + transpose to [b][c][n] fp32 ----------------
__global__ void finalT(const bf16* __restrict__ h5, const float* __restrict__ scbiF,
                       float* __restrict__ out)
{
    __shared__ float ls[64][65];
    int t = threadIdx.x;
    int b = blockIdx.z, n0 = blockIdx.x*64, c0 = blockIdx.y*64;
    int j = t & 63, i0 = t >> 6;
    float sc = scbiF[2*(c0+j)], bi = scbiF[2*(c0+j)+1];
    const unsigned short* hp = reinterpret_cast<const unsigned short*>(h5);
    for (int it = 0; it < 16; ++it) {
        int i = i0 + it*4;
        float v = bfu2f(hp[((size_t)(b*NPTS + n0 + i))*512 + c0 + j]);
        ls[i][j] = fmaxf(fmaf(v, sc, bi), 0.f);
    }
    __syncthreads();
    for (int it = 0; it < 16; ++it) {
        int cr = i0 + it*4;
        out[((size_t)b*512 + c0 + cr)*NPTS + n0 + j] = ls[j][cr];
    }
}

extern "C" void kernel_launch(void* const* d_in, const int* in_sizes, int n_in,
                              void* d_out, int out_size, void* d_ws, size_t ws_size,
                              hipStream_t stream)
{
    const float* x  = (const float*)d_in[0];
    const float* W1 = (const float*)d_in[2];
    const float* W2 = (const float*)d_in[3];
    const float* W3 = (const float*)d_in[4];
    const float* W4 = (const float*)d_in[5];
    const float* W5 = (const float*)d_in[6];
    const float* g1 = (const float*)d_in[7];  const float* b1 = (const float*)d_in[8];
    const float* g2 = (const float*)d_in[9];  const float* b2 = (const float*)d_in[10];
    const float* g3 = (const float*)d_in[11]; const float* b3 = (const float*)d_in[12];
    const float* g4 = (const float*)d_in[13]; const float* b4 = (const float*)d_in[14];
    const float* g5 = (const float*)d_in[15]; const float* b5 = (const float*)d_in[16];
    float* out = (float*)d_out;

    // workspace layout (~178 MiB):
    char* w = (char*)d_ws;
    int*   idx    = (int*)w;                          // 1,310,720 B
    float* scbiF  = (float*)(w + 1323008);            // [5][512][2] f32
    float* shadow = (float*)(w + 1343488);            // [5][16][1024] f32
    short* Wb     = (short*)(w + 1671168);            // bf16 weights (swizzled)
    bf16*  h1     = (bf16*)(w + 2285568);             // [P4][64]   42MB
    float* pmax   = (float*)h1;                       // alias h1 (dead) [16384][256]
    float* pmin   = pmax + (size_t)BN_TOT*256;
    bf16*  h2     = (bf16*)(w + 44228608);            // [P4][64]   42MB
    bf16*  h5     = h2;                               // alias h2 (dead) [16384][512]
    bf16*  h3     = (bf16*)(w + 86171648);            // [P4][128]  84MB
    bf16*  catT   = (bf16*)(w + 170057728);           // [16384][512] 16.8MB

    short* Wb2 = Wb, *Wb3 = Wb + 4096, *Wb4 = Wb + 12288, *Wb5 = Wb + 45056;
    float* sh1 = shadow, *sh2 = shadow + 16384, *sh3 = shadow + 2*16384,
         * sh4 = shadow + 3*16384, *sh5 = shadow + 4*16384;

    initK<<<320, 256, 0, stream>>>(shadow);
    cvtWS<<<16,   256, 0, stream>>>(W2, Wb2, 64);
    cvtWS<<<32,   256, 0, stream>>>(W3, Wb3, 64);
    cvtWS<<<128,  256, 0, stream>>>(W4, Wb4, 128);
    cvtWS<<<1024, 256, 0, stream>>>(W5, Wb5, 512);

    knn_kernel<<<BATCH*NPTS/4, 512, 0, stream>>>(x, idx);   // 2 waves per point
    conv1T<<<P4/256, 256, 0, stream>>>(x, idx, W1, h1, sh1);   // fused layer-1 stats

    fin_kernel<<<1, 256, 0, stream>>>(sh1, g1, b1, scbiF, 64, 1.f/P4);
    maxpoolT<64><<<BN_TOT/4, 256, 0, stream>>>(h1, scbiF, catT, 0);   // + act write-back

    // layer 2: reads pre-activated h1
    gemmT<64,64,2,0,1,64,256,1><<<dim3(P4/128,1), 256, 0, stream>>>(
        Wb2, h1, h2, sh2, nullptr, nullptr);
    fin_kernel<<<1, 256, 0, stream>>>(sh2, g2, b2, scbiF + 1024, 64, 1.f/P4);
    maxpoolT<64><<<BN_TOT/4, 256, 0, stream>>>(h2, scbiF + 1024, catT, 64);

    // layer 3: NSPLIT=1 (NT=8) -> h2 read once
    gemmT<128,64,2,0,1,64,256,1><<<dim3(P4/128,1), 256, 0, stream>>>(
        Wb3, h2, h3, sh3, nullptr, nullptr);
    fin_kernel<<<1, 256, 0, stream>>>(sh3, g3, b3, scbiF + 2048, 128, 1.f/P4);
    maxpoolT<128><<<BN_TOT/2, 256, 0, stream>>>(h3, scbiF + 2048, catT, 128);

    // layer 4: BT=640 (ROWS=320, 16 whole k-groups), NSPLIT=2
    gemmT<256,128,2,1,2,128,640,1><<<dim3(P4/320,2), 640, 0, stream>>>(
        Wb4, h3, nullptr, sh4, pmax, pmin);
    fin_kernel<<<1, 256, 0, stream>>>(sh4, g4, b4, scbiF + 3072, 256, 1.f/P4);
    cat4T<<<BN_TOT, 256, 0, stream>>>(pmax, pmin, scbiF + 3072, g4, catT);

    // layer 5: NSPLIT=4 (NT=8), K tiled 4x128, W 16KB
    gemmT<512,512,2,0,4,128,256,1><<<dim3(BN_TOT/128,4), 256, 0, stream>>>(
        Wb5, catT, h5, sh5, nullptr, nullptr);
    fin_kernel<<<1, 256, 0, stream>>>(sh5, g5, b5, scbiF + 4096, 512, 1.f/BN_TOT);
    finalT<<<dim3(NPTS/64, 8, BATCH), 256, 0, stream>>>(h5, scbiF + 4096, out);
}

// Round 16
// 363.410 us; speedup vs baseline: 1.1015x; 1.1015x over previous
//
#include <hip/hip_runtime.h>
#include <hip/hip_bf16.h>

typedef __hip_bfloat16 bf16;
typedef __attribute__((ext_vector_type(8))) short short8v;
typedef __attribute__((ext_vector_type(4))) float f32x4;
typedef unsigned int uint;
typedef unsigned long long u64;

#define BATCH 8
#define NPTS 2048
#define KNN 20
#define NK (NPTS*KNN)      // 40960
#define P4 (BATCH*NK)      // 327680
#define BN_TOT (BATCH*NPTS) // 16384

union BU { bf16 h; unsigned short u; };
__device__ __forceinline__ unsigned short f2bf(float f){
    BU bu; bu.h = __float2bfloat16(f); return bu.u;
}
__device__ __forceinline__ float bfu2f(unsigned short u){
    return __uint_as_float(((uint)u) << 16);
}
// monotone flip encoding: unsigned compare == float compare
__device__ __forceinline__ uint fenc(float f){
    uint b = __float_as_uint(f);
    return (b & 0x80000000u) ? ~b : (b | 0x80000000u);
}

// ---------------- init: zero shadow stats ----------------
__global__ void initK(float* __restrict__ shadow)
{
    int t = blockIdx.x*256 + threadIdx.x;
    if (t < 5*16*1024) shadow[t] = 0.f;
}

// convert W to bf16 with per-row XOR swizzle on the k index (T2-style):
// dst[co][ci ^ ((co&7)<<3)] = bf16(src[co][ci]).  Read back with same XOR.
__global__ void cvtWS(const float* __restrict__ src, short* __restrict__ dst, int Cin)
{
    int t = blockIdx.x*256 + threadIdx.x;
    int co = t / Cin, ci = t - co*Cin;
    dst[(size_t)co*Cin + (ci ^ ((co & 7) << 3))] = (short)f2bf(src[t]);
}

// ---------------- KNN v5 (r14-verified): prefetch-pipelined scan, dual 4-chains, u64 merge ----------------
__global__ __launch_bounds__(512)
void knn_kernel(const float* __restrict__ x, int* __restrict__ idx)
{
    #pragma clang fp contract(off)
    __shared__ float4 sp[NPTS];               // (x,y,z,xx)  32 KB
    const int b  = blockIdx.x / (NPTS/8);
    const int nb = blockIdx.x % (NPTS/8);
    const float* xb = x + (size_t)b*3*NPTS;
    for (int i = threadIdx.x; i < NPTS; i += 512) {
        float y0 = xb[i], y1 = xb[NPTS+i], y2 = xb[2*NPTS+i];
        float4 p; p.x = y0; p.y = y1; p.z = y2;
        p.w = y0*y0 + y1*y1 + y2*y2;          // same op order as original xxm
        sp[i] = p;
    }
    __syncthreads();

    const int wave = threadIdx.x >> 6;
    const int lane = threadIdx.x & 63;
    const int n = nb*8 + wave;

    const float4 pn = sp[n];
    const float x0 = pn.x, x1 = pn.y, x2 = pn.z;
    const float xxn = pn.w;

    constexpr int L = 4;
    float bA[L], bB[L]; int iA[L], iB[L];
    #pragma unroll
    for (int i = 0; i < L; ++i) {
        bA[i] = -3e38f; bB[i] = -3e38f; iA[i] = 0x7fffffff; iB[i] = 0x7fffffff;
    }

    // software-pipelined scan: pair t+1 loaded before processing pair t
    float4 c0 = sp[lane], c1 = sp[lane + 64];
    #pragma unroll
    for (int t = 0; t < NPTS/128; ++t) {
        float4 n0, n1;
        if (t + 1 < NPTS/128) {
            n0 = sp[lane + (2*t+2)*64];
            n1 = sp[lane + (2*t+3)*64];
        }
        int m0 = lane + (2*t)*64, m1 = m0 + 64;
        float dot0 = x0*c0.x + x1*c0.y + x2*c0.z;
        float v0 = -xxn - (-2.f*dot0) - c0.w;
        float dot1 = x0*c1.x + x1*c1.y + x2*c1.z;
        float v1 = -xxn - (-2.f*dot1) - c1.w;
        int mi0 = m0, mi1 = m1;
        #pragma unroll
        for (int i = 0; i < L; ++i) {         // two independent chains -> ILP
            { bool sw = v0 > bA[i];
              float tv = sw ? bA[i] : v0; int ti = sw ? iA[i] : mi0;
              bA[i] = sw ? v0 : bA[i]; iA[i] = sw ? mi0 : iA[i]; v0 = tv; mi0 = ti; }
            { bool sw = v1 > bB[i];
              float tv = sw ? bB[i] : v1; int ti = sw ? iB[i] : mi1;
              bB[i] = sw ? v1 : bB[i]; iB[i] = sw ? mi1 : iB[i]; v1 = tv; mi1 = ti; }
        }
        c0 = n0; c1 = n1;
    }

    // pack to u64 keys
    u64 kA[L], kB[L];
    #pragma unroll
    for (int i = 0; i < L; ++i) {
        kA[i] = ((u64)fenc(bA[i]) << 32) | (uint)(~iA[i]);
        kB[i] = ((u64)fenc(bB[i]) << 32) | (uint)(~iB[i]);
    }

    size_t obase = ((size_t)b*NPTS + n)*KNN;
    int popA = 0, popB = 0;
    #pragma unroll 1
    for (int s = 0; s < KNN; ++s) {
        bool useA = kA[0] >= kB[0];
        u64 my = useA ? kA[0] : kB[0];
        u64 g = my;
        #pragma unroll
        for (int off = 1; off < 64; off <<= 1) {
            u64 o = __shfl_xor(g, off);
            g = (o > g) ? o : g;
        }
        if (lane == 0) idx[obase + s] = (int)(~(uint)g);
        bool win = (my == g);
        bool pA = win && useA, pB = win && !useA;
        #pragma unroll
        for (int i = 0; i < L-1; ++i) {
            kA[i] = pA ? kA[i+1] : kA[i];
            kB[i] = pB ? kB[i+1] : kB[i];
        }
        kA[L-1] = pA ? 0ULL : kA[L-1];
        kB[L-1] = pB ? 0ULL : kB[L-1];
        popA += pA; popB += pB;
    }

    if (__any((popA >= L) || (popB >= L))) {
        // exact fallback: verified 20-chain + 20-round lexicographic merge
        float B[KNN]; int BI[KNN];
        #pragma unroll
        for (int i = 0; i < KNN; ++i) { B[i] = -3e38f; BI[i] = 0x7fffffff; }
        #pragma unroll 1
        for (int j = 0; j < NPTS/64; ++j) {
            int m = lane + j*64;
            float4 p = sp[m];
            float dot = x0*p.x + x1*p.y + x2*p.z;
            float v = -xxn - (-2.f*dot) - p.w;
            int mi = m;
            #pragma unroll
            for (int i = 0; i < KNN; ++i) {
                bool sw = v > B[i];
                float tv = sw ? B[i]  : v;
                int   ti = sw ? BI[i] : mi;
                B[i]  = sw ? v  : B[i];
                BI[i] = sw ? mi : BI[i];
                v = tv; mi = ti;
            }
        }
        #pragma unroll 1
        for (int s = 0; s < KNN; ++s) {
            float mv = B[0]; int mi = BI[0];
            #pragma unroll
            for (int off = 1; off < 64; off <<= 1) {
                float ov = __shfl_xor(mv, off);
                int   oi = __shfl_xor(mi, off);
                if (ov > mv || (ov == mv && oi < mi)) { mv = ov; mi = oi; }
            }
            bool win = (B[0] == mv) && (BI[0] == mi);
            #pragma unroll
            for (int i = 0; i < KNN-1; ++i) {
                B[i]  = win ? B[i+1]  : B[i];
                BI[i] = win ? BI[i+1] : BI[i];
            }
            B[KNN-1]  = win ? -3e38f     : B[KNN-1];
            BI[KNN-1] = win ? 0x7fffffff : BI[KNN-1];
            if (lane == 0) idx[obase + s] = mi;
        }
    }
}

// ---------------- conv1: edge features + 6->64 conv + FUSED layer-1 stats ----------------
__global__ __launch_bounds__(256)
void conv1T(const float* __restrict__ x, const int* __restrict__ idx,
            const float* __restrict__ W1, bf16* __restrict__ h1,
            float* __restrict__ shadow)
{
    __shared__ unsigned short lv[256][64];   // 32 KB row mirror for stats
    __shared__ float ps[4][64], pq[4][64];
    const int tid = threadIdx.x;
    int p = blockIdx.x*256 + tid;
    int b = p / NK;
    int r = p - b*NK;
    int n = r / KNN;
    int j = idx[p];
    const float* xb = x + (size_t)b*3*NPTS;
    float c0 = xb[n], c1 = xb[NPTS+n], c2 = xb[2*NPTS+n];
    float d0 = xb[j]-c0, d1 = xb[NPTS+j]-c1, d2 = xb[2*NPTS+j]-c2;
    uint4* outp = reinterpret_cast<uint4*>(reinterpret_cast<unsigned short*>(h1) + (size_t)p*64);
    uint4* lrow = reinterpret_cast<uint4*>(lv[tid]);
    #pragma unroll
    for (int ch = 0; ch < 8; ++ch) {
        uint u[4];
        #pragma unroll
        for (int q = 0; q < 4; ++q) {
            const float* wa = W1 + (ch*8 + q*2)*6;
            float a0 = wa[0]*d0 + wa[1]*d1 + wa[2]*d2 + wa[3]*c0 + wa[4]*c1 + wa[5]*c2;
            const float* wb = wa + 6;
            float a1 = wb[0]*d0 + wb[1]*d1 + wb[2]*d2 + wb[3]*c0 + wb[4]*c1 + wb[5]*c2;
            u[q] = (uint)f2bf(a0) | ((uint)f2bf(a1) << 16);
        }
        uint4 val = make_uint4(u[0], u[1], u[2], u[3]);
        outp[ch] = val;
        lrow[ch] = val;
    }
    __syncthreads();
    // transpose-reduce: thread (grp,c) sums 64 rows of channel c (2-way bank, free)
    int c = tid & 63, grp = tid >> 6;
    float s = 0.f, q = 0.f;
    #pragma unroll 8
    for (int i = 0; i < 64; ++i) {
        float v = bfu2f(lv[grp*64 + i][c]);
        s += v; q += v*v;
    }
    ps[grp][c] = s; pq[grp][c] = q;
    __syncthreads();
    if (tid < 64) {
        float S = ps[0][tid]+ps[1][tid]+ps[2][tid]+ps[3][tid];
        float Q = pq[0][tid]+pq[1][tid]+pq[2][tid]+pq[3][tid];
        float* sh = shadow + (size_t)(blockIdx.x & 15)*1024;
        atomicAdd(&sh[tid], S);
        atomicAdd(&sh[512 + tid], Q);
    }
}

// ---------------- fold shadows -> mean/rstd -> (sc,bi) f32 ----------------
__global__ void fin_kernel(const float* __restrict__ shadow,
                           const float* __restrict__ gamma, const float* __restrict__ beta,
                           float* __restrict__ scbiF, int C, float invCnt)
{
    for (int c = threadIdx.x; c < C; c += 256) {
        float s = 0.f, q = 0.f;
        #pragma unroll
        for (int i = 0; i < 16; ++i) { s += shadow[i*1024 + c]; q += shadow[i*1024 + 512 + c]; }
        float m = s*invCnt;
        float var = q*invCnt - m*m;
        float rs = rsqrtf(var + 1e-5f);
        float sc = rs * gamma[c];
        float bi = fmaf(-m, sc, beta[c]);
        scbiF[2*c] = sc; scbiF[2*c+1] = bi;
    }
}

// ---------------- MFMA GEMM: W in LDS (swizzled), pipelined A; PF=2 = deep A prefetch ----------------
template<int Cout, int Cin, int M, int POOL, int NSPLIT, int KTILE, int BT, int PF>
__global__ __launch_bounds__(BT)
void gemmT(const short* __restrict__ Wb, const bf16* __restrict__ in,
           bf16* __restrict__ outT, float* __restrict__ shadow,
           float* __restrict__ pmax, float* __restrict__ pmin)
{
    constexpr int CSPL = Cout/NSPLIT;
    constexpr int NT   = CSPL/16;
    constexpr int ROWS = (BT/64)*16*M;
    constexpr int KSTOT = Cin/32;
    constexpr int KPT   = KTILE/32;          // k-steps per W tile
    constexpr int NTILE = Cin/KTILE;
    constexpr int NG    = POOL ? ROWS/KNN : 1;
    constexpr size_t WB = (size_t)CSPL*KTILE*2;
    constexpr size_t PB = POOL ? (size_t)2*ROWS*17*4 : 0;
    constexpr size_t SB = WB > PB ? WB : PB;

    __shared__ __align__(16) char smem[SB];
    short* WsmS = reinterpret_cast<short*>(smem);
    float* poolF = reinterpret_cast<float*>(smem);

    const int tid  = threadIdx.x;
    const int lane = tid & 63;
    const int g = lane >> 4, mr = lane & 15;
    const int wid = tid >> 6;
    const int rowBlk = blockIdx.x*ROWS;
    const int rowW   = rowBlk + wid*(16*M);
    const int ntBase = blockIdx.y*CSPL;
    const short* inS = reinterpret_cast<const short*>(in);

    f32x4 acc[M][NT];
    #pragma unroll
    for (int m = 0; m < M; ++m)
    #pragma unroll
    for (int i = 0; i < NT; ++i) acc[m][i] = (f32x4){0.f,0.f,0.f,0.f};

    if constexpr (PF == 2) {
        // deep prefetch: ALL k-steps' A fragments in flight before W-stage (NTILE==1)
        static_assert(NTILE == 1, "PF=2 requires KTILE==Cin");
        short8v aAll[M*KSTOT];
        #pragma unroll
        for (int ks = 0; ks < KSTOT; ++ks)
        #pragma unroll
        for (int m = 0; m < M; ++m)
            aAll[ks*M + m] = *reinterpret_cast<const short8v*>(
                inS + (size_t)(rowW + m*16 + mr)*Cin + ks*32 + 8*g);
        for (int f8 = tid; f8 < CSPL*KTILE/8; f8 += BT) {
            int f = f8*8;
            int row = f / KTILE, col = f - row*KTILE;
            short8v v = *reinterpret_cast<const short8v*>(
                Wb + (size_t)(ntBase + row)*Cin + col);
            *reinterpret_cast<short8v*>(WsmS + f) = v;
        }
        __syncthreads();
        #pragma unroll
        for (int ks = 0; ks < KSTOT; ++ks) {
            const int kx = ks*32 + 8*g;
            #pragma unroll
            for (int nt = 0; nt < NT; ++nt) {
                const int brow = nt*16 + mr;
                short8v bfr = *reinterpret_cast<const short8v*>(
                    WsmS + brow*KTILE + (kx ^ ((mr & 7) << 3)));
                #pragma unroll
                for (int m = 0; m < M; ++m)
                    acc[m][nt] = __builtin_amdgcn_mfma_f32_16x16x32_bf16(
                        aAll[ks*M + m], bfr, acc[m][nt], 0, 0, 0);
            }
        }
    } else {
        short8v a[M], anext[M];
        if (PF) {
            #pragma unroll
            for (int m = 0; m < M; ++m)
                a[m] = *reinterpret_cast<const short8v*>(inS + (size_t)(rowW + m*16 + mr)*Cin + 8*g);
        }
        #pragma unroll 1
        for (int kt = 0; kt < NTILE; ++kt) {
            if (kt) __syncthreads();
            {
                const int ktBase = kt*KTILE;
                for (int f8 = tid; f8 < CSPL*KTILE/8; f8 += BT) {
                    int f = f8*8;
                    int row = f / KTILE, col = f - row*KTILE;
                    short8v v = *reinterpret_cast<const short8v*>(
                        Wb + (size_t)(ntBase + row)*Cin + ktBase + col);
                    *reinterpret_cast<short8v*>(WsmS + f) = v;
                }
            }
            __syncthreads();

            #pragma unroll
            for (int ksl = 0; ksl < KPT; ++ksl) {
                const int ksg = kt*KPT + ksl;
                const int k0 = ksg*32 + 8*g;
                if (!PF) {
                    #pragma unroll
                    for (int m = 0; m < M; ++m)
                        a[m] = *reinterpret_cast<const short8v*>(inS + (size_t)(rowW + m*16 + mr)*Cin + k0);
                } else if (ksg + 1 < KSTOT) {
                    #pragma unroll
                    for (int m = 0; m < M; ++m)
                        anext[m] = *reinterpret_cast<const short8v*>(inS + (size_t)(rowW + m*16 + mr)*Cin + k0 + 32);
                }
                const int kx = ksl*32 + 8*g;           // within tile
                #pragma unroll
                for (int nt = 0; nt < NT; ++nt) {
                    const int brow = nt*16 + mr;
                    short8v bfr = *reinterpret_cast<const short8v*>(
                        WsmS + brow*KTILE + (kx ^ ((mr & 7) << 3)));
                    #pragma unroll
                    for (int m = 0; m < M; ++m)
                        acc[m][nt] = __builtin_amdgcn_mfma_f32_16x16x32_bf16(a[m], bfr, acc[m][nt], 0, 0, 0);
                }
                if (PF) {
                    #pragma unroll
                    for (int m = 0; m < M; ++m) a[m] = anext[m];
                }
            }
        }
    }

    // fused per-channel stats
    float* sh = shadow + (size_t)((blockIdx.x ^ blockIdx.y) & 15)*1024;
    #pragma unroll
    for (int nt = 0; nt < NT; ++nt) {
        float s = 0.f, q = 0.f;
        #pragma unroll
        for (int m = 0; m < M; ++m)
        #pragma unroll
        for (int j = 0; j < 4; ++j) { float v = acc[m][nt][j]; s += v; q += v*v; }
        s += __shfl_xor(s, 16); s += __shfl_xor(s, 32);
        q += __shfl_xor(q, 16); q += __shfl_xor(q, 32);
        if (g == 0) {
            atomicAdd(&sh[ntBase + nt*16 + mr], s);
            atomicAdd(&sh[512 + ntBase + nt*16 + mr], q);
        }
    }

    if (!POOL) {
        #pragma unroll
        for (int m = 0; m < M; ++m)
        #pragma unroll
        for (int nt = 0; nt < NT; ++nt)
        #pragma unroll
        for (int j = 0; j < 4; ++j) {
            size_t row = (size_t)rowW + m*16 + g*4 + j;
            outT[row*Cout + ntBase + nt*16 + mr] = __float2bfloat16(acc[m][nt][j]);
        }
    } else {
        // aligned pooling, 2 nt per pass; all acc indices static (rule #20 safe)
        __syncthreads();
        #pragma unroll
        for (int np = 0; np < NT/2; ++np) {
            #pragma unroll
            for (int hh = 0; hh < 2; ++hh) {
                #pragma unroll
                for (int m = 0; m < M; ++m)
                #pragma unroll
                for (int j = 0; j < 4; ++j) {
                    int row = wid*(16*M) + m*16 + g*4 + j;
                    poolF[hh*(ROWS*17) + row*17 + mr] = acc[m][np*2+hh][j];
                }
            }
            __syncthreads();
            if (tid < 2*NG*16) {
                int hh = tid / (NG*16);
                int gg = (tid >> 4) % NG;
                int cc = tid & 15;
                float mx = -3e38f, mn = 3e38f;
                #pragma unroll
                for (int kk = 0; kk < KNN; ++kk) {
                    float v = poolF[hh*(ROWS*17) + (gg*KNN + kk)*17 + cc];
                    mx = fmaxf(mx, v); mn = fminf(mn, v);
                }
                int grp = rowBlk/KNN + gg;             // flat (b,n)
                int c = ntBase + (np*2 + hh)*16 + cc;
                pmax[(size_t)grp*256 + c] = mx;
                pmin[(size_t)grp*256 + c] = mn;
            }
            __syncthreads();
        }
    }
}

// ---------------- k-maxpool into cat_T + in-place activation write-back ----------------
template<int C>
__global__ void maxpoolT(bf16* __restrict__ h, const float* __restrict__ scbiF,
                         bf16* __restrict__ catT, int coff)
{
    constexpr int PB = 256/C;
    int t = threadIdx.x;
    int c = t & (C-1);
    int bn = blockIdx.x*PB + t/C;
    float sc = scbiF[2*c], bi = scbiF[2*c+1];
    unsigned short* src = reinterpret_cast<unsigned short*>(h) + (size_t)bn*KNN*C + c;
    float best = 0.f;                        // relu floor
    #pragma unroll
    for (int kk = 0; kk < KNN; ++kk) {
        float a = fmaxf(fmaf(bfu2f(src[kk*C]), sc, bi), 0.f);
        src[kk*C] = f2bf(a);                 // write activated value back in place
        best = fmaxf(best, a);
    }
    catT[(size_t)bn*512 + coff + c] = __float2bfloat16(best);
}

// ---------------- layer-4 pooled raw -> BN+ReLU -> cat_T[256:512] ----------------
__global__ void cat4T(const float* __restrict__ pmax, const float* __restrict__ pmin,
                      const float* __restrict__ scbiF, const float* __restrict__ g4,
                      bf16* __restrict__ catT)
{
    int t = blockIdx.x*256 + threadIdx.x;   // bn*256 + c
    int c = t & 255, bn = t >> 8;
    float sc = scbiF[2*c], bi = scbiF[2*c+1];
    float v = (g4[c] >= 0.f) ? pmax[t] : pmin[t];
    catT[(size_t)bn*512 + 256 + c] = __float2bfloat16(fmaxf(fmaf(v, sc, bi), 0.f));
}

// ---------------- final BN+ReLU + transpose to [b][c][n] fp32 ----------------
__global__ void finalT(const bf16* __restrict__ h5, const float* __restrict__ scbiF,
                       float* __restrict__ out)
{
    __shared__ float ls[64][65];
    int t = threadIdx.x;
    int b = blockIdx.z, n0 = blockIdx.x*64, c0 = blockIdx.y*64;
    int j = t & 63, i0 = t >> 6;
    float sc = scbiF[2*(c0+j)], bi = scbiF[2*(c0+j)+1];
    const unsigned short* hp = reinterpret_cast<const unsigned short*>(h5);
    for (int it = 0; it < 16; ++it) {
        int i = i0 + it*4;
        float v = bfu2f(hp[((size_t)(b*NPTS + n0 + i))*512 + c0 + j]);
        ls[i][j] = fmaxf(fmaf(v, sc, bi), 0.f);
    }
    __syncthreads();
    for (int it = 0; it < 16; ++it) {
        int cr = i0 + it*4;
        out[((size_t)b*512 + c0 + cr)*NPTS + n0 + j] = ls[j][cr];
    }
}

extern "C" void kernel_launch(void* const* d_in, const int* in_sizes, int n_in,
                              void* d_out, int out_size, void* d_ws, size_t ws_size,
                              hipStream_t stream)
{
    const float* x  = (const float*)d_in[0];
    const float* W1 = (const float*)d_in[2];
    const float* W2 = (const float*)d_in[3];
    const float* W3 = (const float*)d_in[4];
    const float* W4 = (const float*)d_in[5];
    const float* W5 = (const float*)d_in[6];
    const float* g1 = (const float*)d_in[7];  const float* b1 = (const float*)d_in[8];
    const float* g2 = (const float*)d_in[9];  const float* b2 = (const float*)d_in[10];
    const float* g3 = (const float*)d_in[11]; const float* b3 = (const float*)d_in[12];
    const float* g4 = (const float*)d_in[13]; const float* b4 = (const float*)d_in[14];
    const float* g5 = (const float*)d_in[15]; const float* b5 = (const float*)d_in[16];
    float* out = (float*)d_out;

    // workspace layout (~178 MiB):
    char* w = (char*)d_ws;
    int*   idx    = (int*)w;                          // 1,310,720 B
    float* scbiF  = (float*)(w + 1323008);            // [5][512][2] f32
    float* shadow = (float*)(w + 1343488);            // [5][16][1024] f32
    short* Wb     = (short*)(w + 1671168);            // bf16 weights (swizzled)
    bf16*  h1     = (bf16*)(w + 2285568);             // [P4][64]   42MB
    float* pmax   = (float*)h1;                       // alias h1 (dead) [16384][256]
    float* pmin   = pmax + (size_t)BN_TOT*256;
    bf16*  h2     = (bf16*)(w + 44228608);            // [P4][64]   42MB
    bf16*  h5     = h2;                               // alias h2 (dead) [16384][512]
    bf16*  h3     = (bf16*)(w + 86171648);            // [P4][128]  84MB
    bf16*  catT   = (bf16*)(w + 170057728);           // [16384][512] 16.8MB

    short* Wb2 = Wb, *Wb3 = Wb + 4096, *Wb4 = Wb + 12288, *Wb5 = Wb + 45056;
    float* sh1 = shadow, *sh2 = shadow + 16384, *sh3 = shadow + 2*16384,
         * sh4 = shadow + 3*16384, *sh5 = shadow + 4*16384;

    initK<<<320, 256, 0, stream>>>(shadow);
    cvtWS<<<16,   256, 0, stream>>>(W2, Wb2, 64);
    cvtWS<<<32,   256, 0, stream>>>(W3, Wb3, 64);
    cvtWS<<<128,  256, 0, stream>>>(W4, Wb4, 128);
    cvtWS<<<1024, 256, 0, stream>>>(W5, Wb5, 512);

    knn_kernel<<<BATCH*NPTS/8, 512, 0, stream>>>(x, idx);      // v5 (verified)
    conv1T<<<P4/256, 256, 0, stream>>>(x, idx, W1, h1, sh1);   // fused layer-1 stats

    fin_kernel<<<1, 256, 0, stream>>>(sh1, g1, b1, scbiF, 64, 1.f/P4);
    maxpoolT<64><<<BN_TOT/4, 256, 0, stream>>>(h1, scbiF, catT, 0);   // + act write-back

    // layer 2: reads pre-activated h1
    gemmT<64,64,2,0,1,64,256,1><<<dim3(P4/128,1), 256, 0, stream>>>(
        Wb2, h1, h2, sh2, nullptr, nullptr);
    fin_kernel<<<1, 256, 0, stream>>>(sh2, g2, b2, scbiF + 1024, 64, 1.f/P4);
    maxpoolT<64><<<BN_TOT/4, 256, 0, stream>>>(h2, scbiF + 1024, catT, 64);

    // layer 3: NSPLIT=1 (NT=8) -> h2 read once
    gemmT<128,64,2,0,1,64,256,1><<<dim3(P4/128,1), 256, 0, stream>>>(
        Wb3, h2, h3, sh3, nullptr, nullptr);
    fin_kernel<<<1, 256, 0, stream>>>(sh3, g3, b3, scbiF + 2048, 128, 1.f/P4);
    maxpoolT<128><<<BN_TOT/2, 256, 0, stream>>>(h3, scbiF + 2048, catT, 128);

    // layer 4: BT=640 (ROWS=320), NSPLIT=2, PF=2 deep A prefetch (all 4 k-steps)
    gemmT<256,128,2,1,2,128,640,2><<<dim3(P4/320,2), 640, 0, stream>>>(
        Wb4, h3, nullptr, sh4, pmax, pmin);
    fin_kernel<<<1, 256, 0, stream>>>(sh4, g4, b4, scbiF + 3072, 256, 1.f/P4);
    cat4T<<<BN_TOT, 256, 0, stream>>>(pmax, pmin, scbiF + 3072, g4, catT);

    // layer 5: NSPLIT=4 (NT=8), K tiled 4x128, W 16KB
    gemmT<512,512,2,0,4,128,256,1><<<dim3(BN_TOT/128,4), 256, 0, stream>>>(
        Wb5, catT, h5, sh5, nullptr, nullptr);
    fin_kernel<<<1, 256, 0, stream>>>(sh5, g5, b5, scbiF + 4096, 512, 1.f/BN_TOT);
    finalT<<<dim3(NPTS/64, 8, BATCH), 256, 0, stream>>>(h5, scbiF + 4096, out);
}

// Round 17
// 336.729 us; speedup vs baseline: 1.1888x; 1.0792x over previous
//
#include <hip/hip_runtime.h>
#include <hip/hip_bf16.h>

typedef __hip_bfloat16 bf16;
typedef __attribute__((ext_vector_type(8))) short short8v;
typedef __attribute__((ext_vector_type(4))) float f32x4;
typedef unsigned int uint;
typedef unsigned long long u64;

#define BATCH 8
#define NPTS 2048
#define KNN 20
#define NK (NPTS*KNN)      // 40960
#define P4 (BATCH*NK)      // 327680
#define BN_TOT (BATCH*NPTS) // 16384

union BU { bf16 h; unsigned short u; };
__device__ __forceinline__ unsigned short f2bf(float f){
    BU bu; bu.h = __float2bfloat16(f); return bu.u;
}
__device__ __forceinline__ float bfu2f(unsigned short u){
    return __uint_as_float(((uint)u) << 16);
}
// monotone flip encoding: unsigned compare == float compare
__device__ __forceinline__ uint fenc(float f){
    uint b = __float_as_uint(f);
    return (b & 0x80000000u) ? ~b : (b | 0x80000000u);
}

// ---------------- prep: zero shadows + convert all W to swizzled bf16 (one kernel) ----------------
__device__ __forceinline__ void cvt1(const float* src, short* dst, int t, int Cin)
{
    int co = t / Cin, ci = t - co*Cin;
    dst[(size_t)co*Cin + (ci ^ ((co & 7) << 3))] = (short)f2bf(src[t]);
}
__global__ void prepK(const float* __restrict__ W2, const float* __restrict__ W3,
                      const float* __restrict__ W4, const float* __restrict__ W5,
                      float* __restrict__ shadow,
                      short* __restrict__ Wb2, short* __restrict__ Wb3,
                      short* __restrict__ Wb4, short* __restrict__ Wb5)
{
    int blk = blockIdx.x, tid = threadIdx.x;
    if (blk < 320)      { shadow[blk*256 + tid] = 0.f; }
    else if (blk < 336) { cvt1(W2, Wb2, (blk-320)*256 + tid, 64); }
    else if (blk < 368) { cvt1(W3, Wb3, (blk-336)*256 + tid, 64); }
    else if (blk < 496) { cvt1(W4, Wb4, (blk-368)*256 + tid, 128); }
    else                { cvt1(W5, Wb5, (blk-496)*256 + tid, 512); }
}

// ---------------- KNN v7: v5 scan + 32-bit butterfly merge with tie ballot ----------------
__global__ __launch_bounds__(512)
void knn_kernel(const float* __restrict__ x, int* __restrict__ idx)
{
    #pragma clang fp contract(off)
    __shared__ float4 sp[NPTS];               // (x,y,z,xx)  32 KB
    const int b  = blockIdx.x / (NPTS/8);
    const int nb = blockIdx.x % (NPTS/8);
    const float* xb = x + (size_t)b*3*NPTS;
    for (int i = threadIdx.x; i < NPTS; i += 512) {
        float y0 = xb[i], y1 = xb[NPTS+i], y2 = xb[2*NPTS+i];
        float4 p; p.x = y0; p.y = y1; p.z = y2;
        p.w = y0*y0 + y1*y1 + y2*y2;          // same op order as original xxm
        sp[i] = p;
    }
    __syncthreads();

    const int wave = threadIdx.x >> 6;
    const int lane = threadIdx.x & 63;
    const int n = nb*8 + wave;

    const float4 pn = sp[n];
    const float x0 = pn.x, x1 = pn.y, x2 = pn.z;
    const float xxn = pn.w;

    constexpr int L = 4;
    float bA[L], bB[L]; int iA[L], iB[L];
    #pragma unroll
    for (int i = 0; i < L; ++i) {
        bA[i] = -3e38f; bB[i] = -3e38f; iA[i] = 0x7fffffff; iB[i] = 0x7fffffff;
    }

    // software-pipelined scan: pair t+1 loaded before processing pair t
    float4 c0 = sp[lane], c1 = sp[lane + 64];
    #pragma unroll
    for (int t = 0; t < NPTS/128; ++t) {
        float4 n0, n1;
        if (t + 1 < NPTS/128) {
            n0 = sp[lane + (2*t+2)*64];
            n1 = sp[lane + (2*t+3)*64];
        }
        int m0 = lane + (2*t)*64, m1 = m0 + 64;
        float dot0 = x0*c0.x + x1*c0.y + x2*c0.z;
        float v0 = -xxn - (-2.f*dot0) - c0.w;
        float dot1 = x0*c1.x + x1*c1.y + x2*c1.z;
        float v1 = -xxn - (-2.f*dot1) - c1.w;
        int mi0 = m0, mi1 = m1;
        #pragma unroll
        for (int i = 0; i < L; ++i) {         // two independent chains -> ILP
            { bool sw = v0 > bA[i];
              float tv = sw ? bA[i] : v0; int ti = sw ? iA[i] : mi0;
              bA[i] = sw ? v0 : bA[i]; iA[i] = sw ? mi0 : iA[i]; v0 = tv; mi0 = ti; }
            { bool sw = v1 > bB[i];
              float tv = sw ? bB[i] : v1; int ti = sw ? iB[i] : mi1;
              bB[i] = sw ? v1 : bB[i]; iB[i] = sw ? mi1 : iB[i]; v1 = tv; mi1 = ti; }
        }
        c0 = n0; c1 = n1;
    }

    // pack to u64 keys
    u64 kA[L], kB[L];
    #pragma unroll
    for (int i = 0; i < L; ++i) {
        kA[i] = ((u64)fenc(bA[i]) << 32) | (uint)(~iA[i]);
        kB[i] = ((u64)fenc(bB[i]) << 32) | (uint)(~iB[i]);
    }

    size_t obase = ((size_t)b*NPTS + n)*KNN;
    int popA = 0, popB = 0;
    #pragma unroll 1
    for (int s = 0; s < KNN; ++s) {
        bool useA = kA[0] >= kB[0];
        u64 my = useA ? kA[0] : kB[0];
        uint vhi = (uint)(my >> 32);
        uint gh = vhi;
        #pragma unroll
        for (int off = 1; off < 64; off <<= 1) {
            uint o = __shfl_xor(gh, off);
            gh = (o > gh) ? o : gh;
        }
        u64 tie = __ballot(vhi == gh);
        uint glo;
        if (__popcll(tie) == 1) {
            int wl = __ffsll((long long)tie) - 1;
            glo = __shfl((uint)my, wl);
        } else {
            uint lo = (vhi == gh) ? (uint)my : 0u;   // max ~idx == min idx among ties
            #pragma unroll
            for (int off = 1; off < 64; off <<= 1) {
                uint o = __shfl_xor(lo, off);
                lo = (o > lo) ? o : lo;
            }
            glo = lo;
        }
        u64 g = ((u64)gh << 32) | glo;
        if (lane == 0) idx[obase + s] = (int)(~glo);
        bool win = (my == g);
        bool pA = win && useA, pB = win && !useA;
        #pragma unroll
        for (int i = 0; i < L-1; ++i) {
            kA[i] = pA ? kA[i+1] : kA[i];
            kB[i] = pB ? kB[i+1] : kB[i];
        }
        kA[L-1] = pA ? 0ULL : kA[L-1];
        kB[L-1] = pB ? 0ULL : kB[L-1];
        popA += pA; popB += pB;
    }

    if (__any((popA >= L) || (popB >= L))) {
        // exact fallback: verified 20-chain + 20-round lexicographic merge
        float B[KNN]; int BI[KNN];
        #pragma unroll
        for (int i = 0; i < KNN; ++i) { B[i] = -3e38f; BI[i] = 0x7fffffff; }
        #pragma unroll 1
        for (int j = 0; j < NPTS/64; ++j) {
            int m = lane + j*64;
            float4 p = sp[m];
            float dot = x0*p.x + x1*p.y + x2*p.z;
            float v = -xxn - (-2.f*dot) - p.w;
            int mi = m;
            #pragma unroll
            for (int i = 0; i < KNN; ++i) {
                bool sw = v > B[i];
                float tv = sw ? B[i]  : v;
                int   ti = sw ? BI[i] : mi;
                B[i]  = sw ? v  : B[i];
                BI[i] = sw ? mi : BI[i];
                v = tv; mi = ti;
            }
        }
        #pragma unroll 1
        for (int s = 0; s < KNN; ++s) {
            float mv = B[0]; int mi = BI[0];
            #pragma unroll
            for (int off = 1; off < 64; off <<= 1) {
                float ov = __shfl_xor(mv, off);
                int   oi = __shfl_xor(mi, off);
                if (ov > mv || (ov == mv && oi < mi)) { mv = ov; mi = oi; }
            }
            bool win = (B[0] == mv) && (BI[0] == mi);
            #pragma unroll
            for (int i = 0; i < KNN-1; ++i) {
                B[i]  = win ? B[i+1]  : B[i];
                BI[i] = win ? BI[i+1] : BI[i];
            }
            B[KNN-1]  = win ? -3e38f     : B[KNN-1];
            BI[KNN-1] = win ? 0x7fffffff : BI[KNN-1];
            if (lane == 0) idx[obase + s] = mi;
        }
    }
}

// ---------------- conv1: edge features + 6->64 conv + FUSED layer-1 stats ----------------
__global__ __launch_bounds__(256)
void conv1T(const float* __restrict__ x, const int* __restrict__ idx,
            const float* __restrict__ W1, bf16* __restrict__ h1,
            float* __restrict__ shadow)
{
    __shared__ unsigned short lv[256][64];   // 32 KB row mirror for stats
    __shared__ float ps[4][64], pq[4][64];
    const int tid = threadIdx.x;
    int p = blockIdx.x*256 + tid;
    int b = p / NK;
    int r = p - b*NK;
    int n = r / KNN;
    int j = idx[p];
    const float* xb = x + (size_t)b*3*NPTS;
    float c0 = xb[n], c1 = xb[NPTS+n], c2 = xb[2*NPTS+n];
    float d0 = xb[j]-c0, d1 = xb[NPTS+j]-c1, d2 = xb[2*NPTS+j]-c2;
    uint4* outp = reinterpret_cast<uint4*>(reinterpret_cast<unsigned short*>(h1) + (size_t)p*64);
    uint4* lrow = reinterpret_cast<uint4*>(lv[tid]);
    #pragma unroll
    for (int ch = 0; ch < 8; ++ch) {
        uint u[4];
        #pragma unroll
        for (int q = 0; q < 4; ++q) {
            const float* wa = W1 + (ch*8 + q*2)*6;
            float a0 = wa[0]*d0 + wa[1]*d1 + wa[2]*d2 + wa[3]*c0 + wa[4]*c1 + wa[5]*c2;
            const float* wb = wa + 6;
            float a1 = wb[0]*d0 + wb[1]*d1 + wb[2]*d2 + wb[3]*c0 + wb[4]*c1 + wb[5]*c2;
            u[q] = (uint)f2bf(a0) | ((uint)f2bf(a1) << 16);
        }
        uint4 val = make_uint4(u[0], u[1], u[2], u[3]);
        outp[ch] = val;
        lrow[ch] = val;
    }
    __syncthreads();
    // transpose-reduce: thread (grp,c) sums 64 rows of channel c (2-way bank, free)
    int c = tid & 63, grp = tid >> 6;
    float s = 0.f, q = 0.f;
    #pragma unroll 8
    for (int i = 0; i < 64; ++i) {
        float v = bfu2f(lv[grp*64 + i][c]);
        s += v; q += v*v;
    }
    ps[grp][c] = s; pq[grp][c] = q;
    __syncthreads();
    if (tid < 64) {
        float S = ps[0][tid]+ps[1][tid]+ps[2][tid]+ps[3][tid];
        float Q = pq[0][tid]+pq[1][tid]+pq[2][tid]+pq[3][tid];
        float* sh = shadow + (size_t)(blockIdx.x & 15)*1024;
        atomicAdd(&sh[tid], S);
        atomicAdd(&sh[512 + tid], Q);
    }
}

// ---------------- MFMA GEMM: W in LDS (swizzled), pipelined A; PF=2 = deep A prefetch ----------------
template<int Cout, int Cin, int M, int POOL, int NSPLIT, int KTILE, int BT, int PF>
__global__ __launch_bounds__(BT)
void gemmT(const short* __restrict__ Wb, const bf16* __restrict__ in,
           bf16* __restrict__ outT, float* __restrict__ shadow,
           float* __restrict__ pmax, float* __restrict__ pmin)
{
    constexpr int CSPL = Cout/NSPLIT;
    constexpr int NT   = CSPL/16;
    constexpr int ROWS = (BT/64)*16*M;
    constexpr int KSTOT = Cin/32;
    constexpr int KPT   = KTILE/32;          // k-steps per W tile
    constexpr int NTILE = Cin/KTILE;
    constexpr int NG    = POOL ? ROWS/KNN : 1;
    constexpr size_t WB = (size_t)CSPL*KTILE*2;
    constexpr size_t PB = POOL ? (size_t)2*ROWS*17*4 : 0;
    constexpr size_t SB = WB > PB ? WB : PB;

    __shared__ __align__(16) char smem[SB];
    short* WsmS = reinterpret_cast<short*>(smem);
    float* poolF = reinterpret_cast<float*>(smem);

    const int tid  = threadIdx.x;
    const int lane = tid & 63;
    const int g = lane >> 4, mr = lane & 15;
    const int wid = tid >> 6;
    const int rowBlk = blockIdx.x*ROWS;
    const int rowW   = rowBlk + wid*(16*M);
    const int ntBase = blockIdx.y*CSPL;
    const short* inS = reinterpret_cast<const short*>(in);

    f32x4 acc[M][NT];
    #pragma unroll
    for (int m = 0; m < M; ++m)
    #pragma unroll
    for (int i = 0; i < NT; ++i) acc[m][i] = (f32x4){0.f,0.f,0.f,0.f};

    if constexpr (PF == 2) {
        // deep prefetch: ALL k-steps' A fragments in flight before W-stage (NTILE==1)
        static_assert(NTILE == 1, "PF=2 requires KTILE==Cin");
        short8v aAll[M*KSTOT];
        #pragma unroll
        for (int ks = 0; ks < KSTOT; ++ks)
        #pragma unroll
        for (int m = 0; m < M; ++m)
            aAll[ks*M + m] = *reinterpret_cast<const short8v*>(
                inS + (size_t)(rowW + m*16 + mr)*Cin + ks*32 + 8*g);
        for (int f8 = tid; f8 < CSPL*KTILE/8; f8 += BT) {
            int f = f8*8;
            int row = f / KTILE, col = f - row*KTILE;
            short8v v = *reinterpret_cast<const short8v*>(
                Wb + (size_t)(ntBase + row)*Cin + col);
            *reinterpret_cast<short8v*>(WsmS + f) = v;
        }
        __syncthreads();
        #pragma unroll
        for (int ks = 0; ks < KSTOT; ++ks) {
            const int kx = ks*32 + 8*g;
            #pragma unroll
            for (int nt = 0; nt < NT; ++nt) {
                const int brow = nt*16 + mr;
                short8v bfr = *reinterpret_cast<const short8v*>(
                    WsmS + brow*KTILE + (kx ^ ((mr & 7) << 3)));
                #pragma unroll
                for (int m = 0; m < M; ++m)
                    acc[m][nt] = __builtin_amdgcn_mfma_f32_16x16x32_bf16(
                        aAll[ks*M + m], bfr, acc[m][nt], 0, 0, 0);
            }
        }
    } else {
        short8v a[M], anext[M];
        if (PF) {
            #pragma unroll
            for (int m = 0; m < M; ++m)
                a[m] = *reinterpret_cast<const short8v*>(inS + (size_t)(rowW + m*16 + mr)*Cin + 8*g);
        }
        #pragma unroll 1
        for (int kt = 0; kt < NTILE; ++kt) {
            if (kt) __syncthreads();
            {
                const int ktBase = kt*KTILE;
                for (int f8 = tid; f8 < CSPL*KTILE/8; f8 += BT) {
                    int f = f8*8;
                    int row = f / KTILE, col = f - row*KTILE;
                    short8v v = *reinterpret_cast<const short8v*>(
                        Wb + (size_t)(ntBase + row)*Cin + ktBase + col);
                    *reinterpret_cast<short8v*>(WsmS + f) = v;
                }
            }
            __syncthreads();

            #pragma unroll
            for (int ksl = 0; ksl < KPT; ++ksl) {
                const int ksg = kt*KPT + ksl;
                const int k0 = ksg*32 + 8*g;
                if (!PF) {
                    #pragma unroll
                    for (int m = 0; m < M; ++m)
                        a[m] = *reinterpret_cast<const short8v*>(inS + (size_t)(rowW + m*16 + mr)*Cin + k0);
                } else if (ksg + 1 < KSTOT) {
                    #pragma unroll
                    for (int m = 0; m < M; ++m)
                        anext[m] = *reinterpret_cast<const short8v*>(inS + (size_t)(rowW + m*16 + mr)*Cin + k0 + 32);
                }
                const int kx = ksl*32 + 8*g;           // within tile
                #pragma unroll
                for (int nt = 0; nt < NT; ++nt) {
                    const int brow = nt*16 + mr;
                    short8v bfr = *reinterpret_cast<const short8v*>(
                        WsmS + brow*KTILE + (kx ^ ((mr & 7) << 3)));
                    #pragma unroll
                    for (int m = 0; m < M; ++m)
                        acc[m][nt] = __builtin_amdgcn_mfma_f32_16x16x32_bf16(a[m], bfr, acc[m][nt], 0, 0, 0);
                }
                if (PF) {
                    #pragma unroll
                    for (int m = 0; m < M; ++m) a[m] = anext[m];
                }
            }
        }
    }

    // fused per-channel stats
    float* sh = shadow + (size_t)((blockIdx.x ^ blockIdx.y) & 15)*1024;
    #pragma unroll
    for (int nt = 0; nt < NT; ++nt) {
        float s = 0.f, q = 0.f;
        #pragma unroll
        for (int m = 0; m < M; ++m)
        #pragma unroll
        for (int j = 0; j < 4; ++j) { float v = acc[m][nt][j]; s += v; q += v*v; }
        s += __shfl_xor(s, 16); s += __shfl_xor(s, 32);
        q += __shfl_xor(q, 16); q += __shfl_xor(q, 32);
        if (g == 0) {
            atomicAdd(&sh[ntBase + nt*16 + mr], s);
            atomicAdd(&sh[512 + ntBase + nt*16 + mr], q);
        }
    }

    if (!POOL) {
        #pragma unroll
        for (int m = 0; m < M; ++m)
        #pragma unroll
        for (int nt = 0; nt < NT; ++nt)
        #pragma unroll
        for (int j = 0; j < 4; ++j) {
            size_t row = (size_t)rowW + m*16 + g*4 + j;
            outT[row*Cout + ntBase + nt*16 + mr] = __float2bfloat16(acc[m][nt][j]);
        }
    } else {
        // aligned pooling, 2 nt per pass; all acc indices static (rule #20 safe)
        __syncthreads();
        #pragma unroll
        for (int np = 0; np < NT/2; ++np) {
            #pragma unroll
            for (int hh = 0; hh < 2; ++hh) {
                #pragma unroll
                for (int m = 0; m < M; ++m)
                #pragma unroll
                for (int j = 0; j < 4; ++j) {
                    int row = wid*(16*M) + m*16 + g*4 + j;
                    poolF[hh*(ROWS*17) + row*17 + mr] = acc[m][np*2+hh][j];
                }
            }
            __syncthreads();
            if (tid < 2*NG*16) {
                int hh = tid / (NG*16);
                int gg = (tid >> 4) % NG;
                int cc = tid & 15;
                float mx = -3e38f, mn = 3e38f;
                #pragma unroll
                for (int kk = 0; kk < KNN; ++kk) {
                    float v = poolF[hh*(ROWS*17) + (gg*KNN + kk)*17 + cc];
                    mx = fmaxf(mx, v); mn = fminf(mn, v);
                }
                int grp = rowBlk/KNN + gg;             // flat (b,n)
                int c = ntBase + (np*2 + hh)*16 + cc;
                pmax[(size_t)grp*256 + c] = mx;
                pmin[(size_t)grp*256 + c] = mn;
            }
            __syncthreads();
        }
    }
}

// ---------------- k-maxpool + INLINE fin + in-place activation write-back ----------------
template<int C>
__global__ void maxpoolT(bf16* __restrict__ h, const float* __restrict__ shadow,
                         const float* __restrict__ gamma, const float* __restrict__ beta,
                         bf16* __restrict__ catT, int coff)
{
    __shared__ float sscbi[2*C];
    constexpr int PB = 256/C;
    int t = threadIdx.x;
    if (t < C) {
        float s = 0.f, q = 0.f;
        #pragma unroll
        for (int i = 0; i < 16; ++i) { s += shadow[i*1024 + t]; q += shadow[i*1024 + 512 + t]; }
        float m = s*(1.f/P4);
        float var = q*(1.f/P4) - m*m;
        float rs = rsqrtf(var + 1e-5f);
        float sc = rs*gamma[t];
        sscbi[2*t] = sc;
        sscbi[2*t+1] = fmaf(-m, sc, beta[t]);
    }
    __syncthreads();
    int c = t & (C-1);
    int bn = blockIdx.x*PB + t/C;
    float sc = sscbi[2*c], bi = sscbi[2*c+1];
    unsigned short* src = reinterpret_cast<unsigned short*>(h) + (size_t)bn*KNN*C + c;
    float best = 0.f;                        // relu floor
    #pragma unroll
    for (int kk = 0; kk < KNN; ++kk) {
        float a = fmaxf(fmaf(bfu2f(src[kk*C]), sc, bi), 0.f);
        src[kk*C] = f2bf(a);                 // write activated value back in place
        best = fmaxf(best, a);
    }
    catT[(size_t)bn*512 + coff + c] = __float2bfloat16(best);
}

// ---------------- layer-4 pooled raw -> INLINE fin -> BN+ReLU -> cat_T[256:512] ----------------
__global__ void cat4T(const float* __restrict__ pmax, const float* __restrict__ pmin,
                      const float* __restrict__ shadow, const float* __restrict__ g4,
                      const float* __restrict__ b4, bf16* __restrict__ catT)
{
    int c = threadIdx.x;                     // 256 threads, one channel each
    float s = 0.f, q = 0.f;
    #pragma unroll
    for (int i = 0; i < 16; ++i) { s += shadow[i*1024 + c]; q += shadow[i*1024 + 512 + c]; }
    float m = s*(1.f/P4);
    float var = q*(1.f/P4) - m*m;
    float rs = rsqrtf(var + 1e-5f);
    float gg = g4[c];
    float sc = rs*gg;
    float bi = fmaf(-m, sc, b4[c]);
    int bn0 = blockIdx.x*16;
    #pragma unroll
    for (int i = 0; i < 16; ++i) {
        int t = (bn0 + i)*256 + c;
        float v = (gg >= 0.f) ? pmax[t] : pmin[t];
        catT[(size_t)(bn0 + i)*512 + 256 + c] = __float2bfloat16(fmaxf(fmaf(v, sc, bi), 0.f));
    }
}

// ---------------- final: INLINE fin + BN+ReLU + transpose to [b][c][n] fp32 ----------------
__global__ void finalT(const bf16* __restrict__ h5, const float* __restrict__ shadow,
                       const float* __restrict__ g5, const float* __restrict__ b5,
                       float* __restrict__ out)
{
    __shared__ float ls[64][65];
    __shared__ float sscbi[128];
    int t = threadIdx.x;
    int b = blockIdx.z, n0 = blockIdx.x*64, c0 = blockIdx.y*64;
    if (t < 64) {
        int c = c0 + t;
        float s = 0.f, q = 0.f;
        #pragma unroll
        for (int i = 0; i < 16; ++i) { s += shadow[i*1024 + c]; q += shadow[i*1024 + 512 + c]; }
        float m = s*(1.f/BN_TOT);
        float var = q*(1.f/BN_TOT) - m*m;
        float rs = rsqrtf(var + 1e-5f);
        float sc = rs*g5[c];
        sscbi[2*t] = sc;
        sscbi[2*t+1] = fmaf(-m, sc, b5[c]);
    }
    __syncthreads();
    int j = t & 63, i0 = t >> 6;
    float sc = sscbi[2*j], bi = sscbi[2*j+1];
    const unsigned short* hp = reinterpret_cast<const unsigned short*>(h5);
    for (int it = 0; it < 16; ++it) {
        int i = i0 + it*4;
        float v = bfu2f(hp[((size_t)(b*NPTS + n0 + i))*512 + c0 + j]);
        ls[i][j] = fmaxf(fmaf(v, sc, bi), 0.f);
    }
    __syncthreads();
    for (int it = 0; it < 16; ++it) {
        int cr = i0 + it*4;
        out[((size_t)b*512 + c0 + cr)*NPTS + n0 + j] = ls[j][cr];
    }
}

extern "C" void kernel_launch(void* const* d_in, const int* in_sizes, int n_in,
                              void* d_out, int out_size, void* d_ws, size_t ws_size,
                              hipStream_t stream)
{
    const float* x  = (const float*)d_in[0];
    const float* W1 = (const float*)d_in[2];
    const float* W2 = (const float*)d_in[3];
    const float* W3 = (const float*)d_in[4];
    const float* W4 = (const float*)d_in[5];
    const float* W5 = (const float*)d_in[6];
    const float* g1 = (const float*)d_in[7];  const float* b1 = (const float*)d_in[8];
    const float* g2 = (const float*)d_in[9];  const float* b2 = (const float*)d_in[10];
    const float* g3 = (const float*)d_in[11]; const float* b3 = (const float*)d_in[12];
    const float* g4 = (const float*)d_in[13]; const float* b4 = (const float*)d_in[14];
    const float* g5 = (const float*)d_in[15]; const float* b5 = (const float*)d_in[16];
    float* out = (float*)d_out;

    // workspace layout (~178 MiB):
    char* w = (char*)d_ws;
    int*   idx    = (int*)w;                          // 1,310,720 B
    float* shadow = (float*)(w + 1343488);            // [5][16][1024] f32
    short* Wb     = (short*)(w + 1671168);            // bf16 weights (swizzled)
    bf16*  h1     = (bf16*)(w + 2285568);             // [P4][64]   42MB
    float* pmax   = (float*)h1;                       // alias h1 (dead) [16384][256]
    float* pmin   = pmax + (size_t)BN_TOT*256;
    bf16*  h2     = (bf16*)(w + 44228608);            // [P4][64]   42MB
    bf16*  h5     = h2;                               // alias h2 (dead) [16384][512]
    bf16*  h3     = (bf16*)(w + 86171648);            // [P4][128]  84MB
    bf16*  catT   = (bf16*)(w + 170057728);           // [16384][512] 16.8MB

    short* Wb2 = Wb, *Wb3 = Wb + 4096, *Wb4 = Wb + 12288, *Wb5 = Wb + 45056;
    float* sh1 = shadow, *sh2 = shadow + 16384, *sh3 = shadow + 2*16384,
         * sh4 = shadow + 3*16384, *sh5 = shadow + 4*16384;

    prepK<<<1520, 256, 0, stream>>>(W2, W3, W4, W5, shadow, Wb2, Wb3, Wb4, Wb5);

    knn_kernel<<<BATCH*NPTS/8, 512, 0, stream>>>(x, idx);
    conv1T<<<P4/256, 256, 0, stream>>>(x, idx, W1, h1, sh1);   // fused layer-1 stats

    maxpoolT<64><<<BN_TOT/4, 256, 0, stream>>>(h1, sh1, g1, b1, catT, 0);

    // layer 2: reads pre-activated h1
    gemmT<64,64,2,0,1,64,256,1><<<dim3(P4/128,1), 256, 0, stream>>>(
        Wb2, h1, h2, sh2, nullptr, nullptr);
    maxpoolT<64><<<BN_TOT/4, 256, 0, stream>>>(h2, sh2, g2, b2, catT, 64);

    // layer 3: NSPLIT=1 (NT=8) -> h2 read once
    gemmT<128,64,2,0,1,64,256,1><<<dim3(P4/128,1), 256, 0, stream>>>(
        Wb3, h2, h3, sh3, nullptr, nullptr);
    maxpoolT<128><<<BN_TOT/2, 256, 0, stream>>>(h3, sh3, g3, b3, catT, 128);

    // layer 4: BT=640 (ROWS=320), NSPLIT=2, PF=2 deep A prefetch
    gemmT<256,128,2,1,2,128,640,2><<<dim3(P4/320,2), 640, 0, stream>>>(
        Wb4, h3, nullptr, sh4, pmax, pmin);
    cat4T<<<BN_TOT/16, 256, 0, stream>>>(pmax, pmin, sh4, g4, b4, catT);

    // layer 5: NSPLIT=4 (NT=8), K tiled 4x128, W 16KB
    gemmT<512,512,2,0,4,128,256,1><<<dim3(BN_TOT/128,4), 256, 0, stream>>>(
        Wb5, catT, h5, sh5, nullptr, nullptr);
    finalT<<<dim3(NPTS/64, 8, BATCH), 256, 0, stream>>>(h5, sh5, g5, b5, out);
}